// Round 12
// baseline (98.343 us; speedup 1.0000x reference)
//
#include <hip/hip_runtime.h>
#include <hip/hip_bf16.h>
#include <cstdint>

#define N_PTS 8192
#define DIM 128
// 64x64 wave tiles over the upper triangle: row-tiles I in [0,128),
// offset(i) = i*(257-i)/2, total 8256 (decode verified in r6).
#define NBLK 8256

// Base-2-domain circle-loss constants (gamma=256, m=0.25, folded log2(e)).
#define KC2 369.3299304675746f    //  256*log2e
#define KC1 -738.6598609351493f   // -512*log2e
#define KC0 346.2468098133512f    //  240*log2e
#define KCN0 -23.083120654223414f // -16*log2e
#define NEGH -1e30f
#define LN2F 0.6931471805599453f

typedef __attribute__((ext_vector_type(8))) __bf16 bf16x8;
typedef __attribute__((ext_vector_type(4))) float f32x4;

// RNE float -> bf16 bits (inputs are finite, no NaN handling needed)
__device__ __forceinline__ unsigned short f2bf(float x) {
  unsigned int u = __float_as_uint(x);
  unsigned int r = (u + 0x7FFFu + ((u >> 16) & 1u)) >> 16;
  return (unsigned short)r;
}

// PANEL-SWIZZLED feature layout (verified r11: the TA-coalescing fix).
// Panels of 16 rows; within panel (elems): [kk:4][kgrp:4][rsel:16][8].
//   addr(row, e) = (row>>4)*2048 + (e>>5)*512 + ((e>>3)&3)*128 + (row&15)*8 + (e&7)
// A fragment load becomes panel*2048 + kk*512 + lane*8: 64 lanes x 16B
// contiguous 1KiB, 16 lines/instr (was 64 lines/instr row-major -> the
// invariant ~40us TA wall of r6-r10).
__global__ __launch_bounds__(256) void normalize_kernel(const float* __restrict__ feat,
                                                        const int* __restrict__ labels,
                                                        unsigned short* __restrict__ fb2,
                                                        unsigned char* __restrict__ lab8) {
  const int gid = blockIdx.x * 256 + threadIdx.x;
  if (gid < N_PTS) lab8[gid] = (unsigned char)labels[gid];
  const int row = blockIdx.x * 8 + (threadIdx.x >> 5);
  const int l32 = threadIdx.x & 31;
  const float4 v = *(const float4*)(feat + row * DIM + l32 * 4);
  float ss = v.x * v.x + v.y * v.y + v.z * v.z + v.w * v.w;
#pragma unroll
  for (int o = 16; o > 0; o >>= 1) ss += __shfl_xor(ss, o);  // stays in 32-group
  const float inv = 1.0f / fmaxf(sqrtf(ss), 1e-12f);
  uint2 pack;
  pack.x = (unsigned int)f2bf(v.x * inv) | ((unsigned int)f2bf(v.y * inv) << 16);
  pack.y = (unsigned int)f2bf(v.z * inv) | ((unsigned int)f2bf(v.w * inv) << 16);
  const int e0 = l32 * 4;  // elems e0..e0+3 (one 8B half of a 16B chunk)
  const int dst = (row >> 4) * 2048 + (e0 >> 5) * 512 + ((e0 >> 3) & 3) * 128 +
                  (row & 15) * 8 + (e0 & 7);
  *(uint2*)(fb2 + dst) = pack;  // 8B aligned
}

// triangular decode over 128 row-tiles (verified r6): offset(i) = i*(257-i)/2
#define DECODE(TID, IV, JV)                                               \
  do {                                                                    \
    int _i = (int)((257.0f - sqrtf(66049.0f - 8.0f * (float)(TID))) * 0.5f); \
    _i = _i < 0 ? 0 : (_i > 127 ? 127 : _i);                              \
    while (_i * (257 - _i) / 2 > (TID)) --_i;                             \
    while ((_i + 1) * (256 - _i) / 2 <= (TID)) ++_i;                      \
    IV = _i;                                                              \
    JV = _i + ((TID)-_i * (257 - _i) / 2);                                \
  } while (0)

// Wave-independent 64x64 tiles, zero LDS, zero barriers, single-buffered
// K-loop over the panel-swizzled layout. vs r11's 32x64: half the tiles
// (fixed costs halve), 1.5x fewer VMEM instrs, same per-element epilogue.
// Register budget: acc 64 + frags 32 + ~28 scalars ~ 124 unified -> 4
// waves/SIMD (single-buffering is what fits 64x64 under the 128 cliff;
// r6's dbuf variant was 176 -> 2 waves).
__global__ __launch_bounds__(256) void pair_kernel(const unsigned short* __restrict__ f,
                                                   const unsigned char* __restrict__ lab8,
                                                   float4* __restrict__ partials) {
  const int lane = threadIdx.x & 63;
  const int tid = blockIdx.x * 4 + (threadIdx.x >> 6);  // tile id, 0..NBLK-1

  int I, J;
  DECODE(tid, I, J);

  const int rsel = lane & 15, kgrp = lane >> 4;

  // panel-swizzled fragment pointers: contiguous 1KiB per fragment load
  const unsigned short* pA = f + (size_t)(I * 4) * 2048 + lane * 8;
  const unsigned short* pB = f + (size_t)(J * 4) * 2048 + lane * 8;

  // epilogue label gathers issued early; latency hides under the K-loop
  const int ibase = I * 64 + kgrp * 4;
  const int jbase = J * 64 + rsel;
  unsigned int liPack[4], ljPack = 0;
#pragma unroll
  for (int tn = 0; tn < 4; ++tn)
    ljPack |= ((unsigned int)lab8[jbase + tn * 16]) << (tn * 8);
#pragma unroll
  for (int tm = 0; tm < 4; ++tm)
    liPack[tm] = *(const unsigned int*)(lab8 + ibase + tm * 16);

  f32x4 acc[4][4];
#pragma unroll
  for (int a = 0; a < 4; ++a)
#pragma unroll
    for (int b = 0; b < 4; ++b) acc[a][b] = (f32x4){0.f, 0.f, 0.f, 0.f};

#pragma unroll 1
  for (int kk = 0; kk < 4; ++kk) {
    bf16x8 fa[4], fbv[4];
#pragma unroll
    for (int x = 0; x < 4; ++x) fa[x] = *(const bf16x8*)(pA + x * 2048 + kk * 512);
#pragma unroll
    for (int x = 0; x < 4; ++x) fbv[x] = *(const bf16x8*)(pB + x * 2048 + kk * 512);
#pragma unroll
    for (int tm = 0; tm < 4; ++tm)
#pragma unroll
      for (int tn = 0; tn < 4; ++tn)
        acc[tm][tn] =
            __builtin_amdgcn_mfma_f32_16x16x32_bf16(fa[tm], fbv[tn], acc[tm][tn], 0, 0, 0);
  }

  // ---- epilogue: circle-loss logits (base-2 domain) + in-wave logsumexp ----
  // C/D mapping (16x16x32): col = lane&15 (j/B side), row = (lane>>4)*4 + reg

  // pass 1: selected logit in-place, per-thread maxes
  float mp = NEGH, mn = NEGH;
  if (J > I) {  // tile fully above the diagonal: all pairs valid (j > i)
#pragma unroll
    for (int tm = 0; tm < 4; ++tm)
#pragma unroll
      for (int tn = 0; tn < 4; ++tn) {
        const unsigned int ljB = (ljPack >> (tn * 8)) & 0xFFu;
#pragma unroll
        for (int r = 0; r < 4; ++r) {
          const float s = acc[tm][tn][r];
          const bool eq = (((liPack[tm] >> (r * 8)) & 0xFFu) == ljB);
          float u = fmaf(s, fmaf(s, KC2, eq ? KC1 : 0.f), eq ? KC0 : KCN0);
          u = (!eq && s <= -0.25f) ? 0.f : u;
          acc[tm][tn][r] = u;
          mp = fmaxf(mp, eq ? u : NEGH);
          mn = fmaxf(mn, eq ? NEGH : u);
        }
      }
  } else {  // diagonal tile (I==J): mask out j <= i
#pragma unroll
    for (int tm = 0; tm < 4; ++tm)
#pragma unroll
      for (int tn = 0; tn < 4; ++tn) {
        const unsigned int ljB = (ljPack >> (tn * 8)) & 0xFFu;
        const int d = (jbase + tn * 16) - (ibase + tm * 16);  // valid iff d > r
#pragma unroll
        for (int r = 0; r < 4; ++r) {
          const float s = acc[tm][tn][r];
          const bool eq = (((liPack[tm] >> (r * 8)) & 0xFFu) == ljB);
          float u = fmaf(s, fmaf(s, KC2, eq ? KC1 : 0.f), eq ? KC0 : KCN0);
          u = (!eq && s <= -0.25f) ? 0.f : u;
          const bool valid = d > r;
          u = valid ? u : NEGH;
          acc[tm][tn][r] = u;
          mp = fmaxf(mp, (eq && valid) ? u : NEGH);
          mn = fmaxf(mn, (!eq && valid) ? u : NEGH);
        }
      }
  }
  // in-wave butterfly: all 64 lanes end with the wave max (no LDS, no barrier)
#pragma unroll
  for (int o = 32; o > 0; o >>= 1) {
    mp = fmaxf(mp, __shfl_xor(mp, o));
    mn = fmaxf(mn, __shfl_xor(mn, o));
  }
  // Clamp keeps exp2(NEGH - M) == 0 even when a stream is empty in this tile.
  const float Mp = fmaxf(mp, -1e28f);
  const float Mn = fmaxf(mn, -1e28f);

  // pass 2: one exp2 per element, route to the owning stream
  float sp = 0.f, sn = 0.f;
#pragma unroll
  for (int tm = 0; tm < 4; ++tm)
#pragma unroll
    for (int tn = 0; tn < 4; ++tn) {
      const unsigned int ljB = (ljPack >> (tn * 8)) & 0xFFu;
#pragma unroll
      for (int r = 0; r < 4; ++r) {
        const bool eq = (((liPack[tm] >> (r * 8)) & 0xFFu) == ljB);
        const float e = __builtin_amdgcn_exp2f(acc[tm][tn][r] - (eq ? Mp : Mn));
        sp += eq ? e : 0.f;
        sn += eq ? 0.f : e;
      }
    }
#pragma unroll
  for (int o = 32; o > 0; o >>= 1) {
    sp += __shfl_xor(sp, o);
    sn += __shfl_xor(sn, o);
  }
  if (lane == 0) partials[tid] = make_float4(Mp, sp, Mn, sn);
}

// Merge 8256 (m2,s2) base-2 partials for both streams; softplus(lse_p+lse_n).
__global__ __launch_bounds__(1024) void finalize_kernel(const float4* __restrict__ partials,
                                                        float* __restrict__ out) {
  const int t = threadIdx.x;
  float mp = NEGH, sp = 0.f, mn = NEGH, sn = 0.f;
  for (int i = t; i < NBLK; i += 1024) {
    const float4 p = partials[i];
    {
      const float m = fmaxf(mp, p.x);
      sp = sp * __builtin_amdgcn_exp2f(mp - m) + p.y * __builtin_amdgcn_exp2f(p.x - m);
      mp = m;
    }
    {
      const float m = fmaxf(mn, p.z);
      sn = sn * __builtin_amdgcn_exp2f(mn - m) + p.w * __builtin_amdgcn_exp2f(p.z - m);
      mn = m;
    }
  }
  __shared__ float smp[1024], ssp[1024], smn[1024], ssn[1024];
  smp[t] = mp; ssp[t] = sp; smn[t] = mn; ssn[t] = sn;
  __syncthreads();
  for (int off = 512; off > 0; off >>= 1) {
    if (t < off) {
      {
        const float m2 = smp[t + off], s2 = ssp[t + off];
        const float m = fmaxf(smp[t], m2);
        ssp[t] = ssp[t] * __builtin_amdgcn_exp2f(smp[t] - m) + s2 * __builtin_amdgcn_exp2f(m2 - m);
        smp[t] = m;
      }
      {
        const float m2 = smn[t + off], s2 = ssn[t + off];
        const float m = fmaxf(smn[t], m2);
        ssn[t] = ssn[t] * __builtin_amdgcn_exp2f(smn[t] - m) + s2 * __builtin_amdgcn_exp2f(m2 - m);
        smn[t] = m;
      }
    }
    __syncthreads();
  }
  if (t == 0) {
    const float lsep = (smp[0] + __builtin_amdgcn_logf(ssp[0])) * LN2F;  // base-2 -> nat
    const float lsen = (smn[0] + __builtin_amdgcn_logf(ssn[0])) * LN2F;
    const float x = lsep + lsen;
    out[0] = fmaxf(x, 0.f) + log1pf(__expf(-fabsf(x)));  // stable softplus
  }
}

extern "C" void kernel_launch(void* const* d_in, const int* in_sizes, int n_in,
                              void* d_out, int out_size, void* d_ws, size_t ws_size,
                              hipStream_t stream) {
  const float* feat = (const float*)d_in[0];
  const int* labels = (const int*)d_in[1];
  float* out = (float*)d_out;

  unsigned short* fb2 = (unsigned short*)d_ws;                       // 2 MiB (panel-swizzled)
  char* base = (char*)d_ws + (size_t)N_PTS * DIM * 2;
  float4* partials = (float4*)base;                                  // 8256*16 = 129 KiB
  unsigned char* lab8 = (unsigned char*)(base + (size_t)NBLK * 16);  // 8192 B

  normalize_kernel<<<N_PTS / 8, 256, 0, stream>>>(feat, labels, fb2, lab8);
  pair_kernel<<<NBLK / 4, 256, 0, stream>>>(fb2, lab8, partials);
  finalize_kernel<<<1, 1024, 0, stream>>>(partials, out);
}

// Round 13
// 94.191 us; speedup vs baseline: 1.0441x; 1.0441x over previous
//
#include <hip/hip_runtime.h>
#include <hip/hip_bf16.h>
#include <cstdint>

#define N_PTS 8192
#define DIM 128
// 32-row x 64-col wave tiles over the upper triangle (verified r7-r11).
// Row-tiles I in [0,256), col-tiles J in [0,128), jmin(I) = I>>1.
#define NBLK 16512

// Base-2-domain circle-loss constants (gamma=256, m=0.25, folded log2(e)).
#define KC2 369.3299304675746f    //  256*log2e
#define KC1 -738.6598609351493f   // -512*log2e
#define KC0 346.2468098133512f    //  240*log2e
#define KCN0 -23.083120654223414f // -16*log2e
#define NEGH -1e30f
#define LN2F 0.6931471805599453f

typedef __attribute__((ext_vector_type(8))) __bf16 bf16x8;
typedef __attribute__((ext_vector_type(4))) float f32x4;

// RNE float -> bf16 bits (inputs are finite, no NaN handling needed)
__device__ __forceinline__ unsigned short f2bf(float x) {
  unsigned int u = __float_as_uint(x);
  unsigned int r = (u + 0x7FFFu + ((u >> 16) & 1u)) >> 16;
  return (unsigned short)r;
}

// PANEL-SWIZZLED feature layout (verified r11: the TA-coalescing fix).
// Panels of 16 rows; within panel (elems): [kk:4][kgrp:4][rsel:16][8].
//   addr(row, e) = (row>>4)*2048 + (e>>5)*512 + ((e>>3)&3)*128 + (row&15)*8 + (e&7)
// A fragment load becomes panel*2048 + kk*512 + lane*8: 64 lanes x 16B
// contiguous 1KiB, 16 lines/instr (was 64 lines/instr row-major -> the
// invariant ~40us TA wall of r6-r10).
__global__ __launch_bounds__(256) void normalize_kernel(const float* __restrict__ feat,
                                                        const int* __restrict__ labels,
                                                        unsigned short* __restrict__ fb2,
                                                        unsigned char* __restrict__ lab8) {
  const int gid = blockIdx.x * 256 + threadIdx.x;
  if (gid < N_PTS) lab8[gid] = (unsigned char)labels[gid];
  const int row = blockIdx.x * 8 + (threadIdx.x >> 5);
  const int l32 = threadIdx.x & 31;
  const float4 v = *(const float4*)(feat + row * DIM + l32 * 4);
  float ss = v.x * v.x + v.y * v.y + v.z * v.z + v.w * v.w;
#pragma unroll
  for (int o = 16; o > 0; o >>= 1) ss += __shfl_xor(ss, o);  // stays in 32-group
  const float inv = 1.0f / fmaxf(sqrtf(ss), 1e-12f);
  uint2 pack;
  pack.x = (unsigned int)f2bf(v.x * inv) | ((unsigned int)f2bf(v.y * inv) << 16);
  pack.y = (unsigned int)f2bf(v.z * inv) | ((unsigned int)f2bf(v.w * inv) << 16);
  const int e0 = l32 * 4;  // elems e0..e0+3 (one 8B half of a 16B chunk)
  const int dst = (row >> 4) * 2048 + (e0 >> 5) * 512 + ((e0 >> 3) & 3) * 128 +
                  (row & 15) * 8 + (e0 & 7);
  *(uint2*)(fb2 + dst) = pack;  // 8B aligned
}

// ---- tile machinery (verified r7-r11) ----
#define OFFI(I) (128 * (I) - (((I) - 1) * ((I) - 1)) / 4)
#define DECODE(TID, IV, JV)                                              \
  do {                                                                   \
    int _i = (int)(2.0f * (128.5f - sqrtf(16512.0f - (float)(TID))));    \
    _i = _i < 0 ? 0 : (_i > 255 ? 255 : _i);                             \
    while (OFFI(_i) > (TID)) --_i;                                       \
    while (OFFI(_i + 1) <= (TID)) ++_i;                                  \
    IV = _i;                                                             \
    JV = (_i >> 1) + ((TID)-OFFI(_i));                                   \
  } while (0)

// Wave-independent 32x64 tiles, zero LDS, zero barriers, panel-swizzled
// coalesced loads (r11, best total) + 2-deep fragment double-buffer in the
// K-loop. The dbuf was NULL in r8 when the TA wall capped everything; with
// coalesced loads it should hide the ~200cy L2 latency per K-step that
// 4 correlated waves/SIMD don't cover. Regs: 2 frag sets 48 + acc 32 +
// ~30 scalars ~ 110 unified -> 4 waves/SIMD (no cliff; r12's 64x64 sat at
// ~128+ and regressed).
__global__ __launch_bounds__(256) void pair_kernel(const unsigned short* __restrict__ f,
                                                   const unsigned char* __restrict__ lab8,
                                                   float4* __restrict__ partials) {
  const int lane = threadIdx.x & 63;
  const int tid = blockIdx.x * 4 + (threadIdx.x >> 6);  // tile id, 0..NBLK-1

  int I, J;
  DECODE(tid, I, J);

  const int rsel = lane & 15, kgrp = lane >> 4;

  // panel-swizzled fragment pointers: contiguous 1KiB per fragment load
  const unsigned short* pA = f + (size_t)(I * 2) * 2048 + lane * 8;
  const unsigned short* pB = f + (size_t)(J * 4) * 2048 + lane * 8;

  // epilogue label gathers issued early; latency hides under the K-loop
  const int ibase = I * 32 + kgrp * 4;
  const int jbase = J * 64 + rsel;
  unsigned int liPack[2], ljPack = 0;
#pragma unroll
  for (int tn = 0; tn < 4; ++tn)
    ljPack |= ((unsigned int)lab8[jbase + tn * 16]) << (tn * 8);
#pragma unroll
  for (int tm = 0; tm < 2; ++tm)
    liPack[tm] = *(const unsigned int*)(lab8 + ibase + tm * 16);

  f32x4 acc[2][4];
#pragma unroll
  for (int a = 0; a < 2; ++a)
#pragma unroll
    for (int b = 0; b < 4; ++b) acc[a][b] = (f32x4){0.f, 0.f, 0.f, 0.f};

#define LOADF(FA, FB, KK)                                                \
  do {                                                                   \
    _Pragma("unroll") for (int x = 0; x < 2; ++x)                        \
        FA[x] = *(const bf16x8*)(pA + x * 2048 + (KK)*512);              \
    _Pragma("unroll") for (int x = 0; x < 4; ++x)                        \
        FB[x] = *(const bf16x8*)(pB + x * 2048 + (KK)*512);              \
  } while (0)
#define MFMA8(FA, FB)                                                    \
  do {                                                                   \
    _Pragma("unroll") for (int tm = 0; tm < 2; ++tm)                     \
        _Pragma("unroll") for (int tn = 0; tn < 4; ++tn)                 \
            acc[tm][tn] = __builtin_amdgcn_mfma_f32_16x16x32_bf16(       \
                FA[tm], FB[tn], acc[tm][tn], 0, 0, 0);                   \
  } while (0)

  {
    bf16x8 xa[2], xb[4], ya[2], yb[4];
    LOADF(xa, xb, 0);
    LOADF(ya, yb, 1);   // 2 K-steps in flight
    MFMA8(xa, xb);
    LOADF(xa, xb, 2);   // issued behind step-0 MFMAs, consumed 2 steps later
    MFMA8(ya, yb);
    LOADF(ya, yb, 3);
    MFMA8(xa, xb);
    MFMA8(ya, yb);
  }
#undef LOADF
#undef MFMA8

  // ---- epilogue: circle-loss logits (base-2 domain) + in-wave logsumexp ----
  // C/D mapping (16x16x32): col = lane&15 (j/B side), row = (lane>>4)*4 + reg

  // pass 1: selected logit in-place, per-thread maxes
  float mp = NEGH, mn = NEGH;
  if (2 * J > I) {  // tile fully above the diagonal: all pairs valid (j > i)
#pragma unroll
    for (int tm = 0; tm < 2; ++tm)
#pragma unroll
      for (int tn = 0; tn < 4; ++tn) {
        const unsigned int ljB = (ljPack >> (tn * 8)) & 0xFFu;
#pragma unroll
        for (int r = 0; r < 4; ++r) {
          const float s = acc[tm][tn][r];
          const bool eq = (((liPack[tm] >> (r * 8)) & 0xFFu) == ljB);
          float u = fmaf(s, fmaf(s, KC2, eq ? KC1 : 0.f), eq ? KC0 : KCN0);
          u = (!eq && s <= -0.25f) ? 0.f : u;
          acc[tm][tn][r] = u;
          mp = fmaxf(mp, eq ? u : NEGH);
          mn = fmaxf(mn, eq ? NEGH : u);
        }
      }
  } else {  // diagonal-straddling tile: mask out j <= i
#pragma unroll
    for (int tm = 0; tm < 2; ++tm)
#pragma unroll
      for (int tn = 0; tn < 4; ++tn) {
        const unsigned int ljB = (ljPack >> (tn * 8)) & 0xFFu;
        const int d = (jbase + tn * 16) - (ibase + tm * 16);  // valid iff d > r
#pragma unroll
        for (int r = 0; r < 4; ++r) {
          const float s = acc[tm][tn][r];
          const bool eq = (((liPack[tm] >> (r * 8)) & 0xFFu) == ljB);
          float u = fmaf(s, fmaf(s, KC2, eq ? KC1 : 0.f), eq ? KC0 : KCN0);
          u = (!eq && s <= -0.25f) ? 0.f : u;
          const bool valid = d > r;
          u = valid ? u : NEGH;
          acc[tm][tn][r] = u;
          mp = fmaxf(mp, (eq && valid) ? u : NEGH);
          mn = fmaxf(mn, (!eq && valid) ? u : NEGH);
        }
      }
  }
  // in-wave butterfly: all 64 lanes end with the wave max (no LDS, no barrier)
#pragma unroll
  for (int o = 32; o > 0; o >>= 1) {
    mp = fmaxf(mp, __shfl_xor(mp, o));
    mn = fmaxf(mn, __shfl_xor(mn, o));
  }
  // Clamp keeps exp2(NEGH - M) == 0 even when a stream is empty in this tile.
  const float Mp = fmaxf(mp, -1e28f);
  const float Mn = fmaxf(mn, -1e28f);

  // pass 2: one exp2 per element, route to the owning stream
  float sp = 0.f, sn = 0.f;
#pragma unroll
  for (int tm = 0; tm < 2; ++tm)
#pragma unroll
    for (int tn = 0; tn < 4; ++tn) {
      const unsigned int ljB = (ljPack >> (tn * 8)) & 0xFFu;
#pragma unroll
      for (int r = 0; r < 4; ++r) {
        const bool eq = (((liPack[tm] >> (r * 8)) & 0xFFu) == ljB);
        const float e = __builtin_amdgcn_exp2f(acc[tm][tn][r] - (eq ? Mp : Mn));
        sp += eq ? e : 0.f;
        sn += eq ? 0.f : e;
      }
    }
#pragma unroll
  for (int o = 32; o > 0; o >>= 1) {
    sp += __shfl_xor(sp, o);
    sn += __shfl_xor(sn, o);
  }
  if (lane == 0) partials[tid] = make_float4(Mp, sp, Mn, sn);
}

// Merge 16512 (m2,s2) base-2 partials for both streams; softplus(lse_p+lse_n).
__global__ __launch_bounds__(1024) void finalize_kernel(const float4* __restrict__ partials,
                                                        float* __restrict__ out) {
  const int t = threadIdx.x;
  float mp = NEGH, sp = 0.f, mn = NEGH, sn = 0.f;
  for (int i = t; i < NBLK; i += 1024) {
    const float4 p = partials[i];
    {
      const float m = fmaxf(mp, p.x);
      sp = sp * __builtin_amdgcn_exp2f(mp - m) + p.y * __builtin_amdgcn_exp2f(p.x - m);
      mp = m;
    }
    {
      const float m = fmaxf(mn, p.z);
      sn = sn * __builtin_amdgcn_exp2f(mn - m) + p.w * __builtin_amdgcn_exp2f(p.z - m);
      mn = m;
    }
  }
  __shared__ float smp[1024], ssp[1024], smn[1024], ssn[1024];
  smp[t] = mp; ssp[t] = sp; smn[t] = mn; ssn[t] = sn;
  __syncthreads();
  for (int off = 512; off > 0; off >>= 1) {
    if (t < off) {
      {
        const float m2 = smp[t + off], s2 = ssp[t + off];
        const float m = fmaxf(smp[t], m2);
        ssp[t] = ssp[t] * __builtin_amdgcn_exp2f(smp[t] - m) + s2 * __builtin_amdgcn_exp2f(m2 - m);
        smp[t] = m;
      }
      {
        const float m2 = smn[t + off], s2 = ssn[t + off];
        const float m = fmaxf(smn[t], m2);
        ssn[t] = ssn[t] * __builtin_amdgcn_exp2f(smn[t] - m) + s2 * __builtin_amdgcn_exp2f(m2 - m);
        smn[t] = m;
      }
    }
    __syncthreads();
  }
  if (t == 0) {
    const float lsep = (smp[0] + __builtin_amdgcn_logf(ssp[0])) * LN2F;  // base-2 -> nat
    const float lsen = (smn[0] + __builtin_amdgcn_logf(ssn[0])) * LN2F;
    const float x = lsep + lsen;
    out[0] = fmaxf(x, 0.f) + log1pf(__expf(-fabsf(x)));  // stable softplus
  }
}

extern "C" void kernel_launch(void* const* d_in, const int* in_sizes, int n_in,
                              void* d_out, int out_size, void* d_ws, size_t ws_size,
                              hipStream_t stream) {
  const float* feat = (const float*)d_in[0];
  const int* labels = (const int*)d_in[1];
  float* out = (float*)d_out;

  unsigned short* fb2 = (unsigned short*)d_ws;                       // 2 MiB (panel-swizzled)
  char* base = (char*)d_ws + (size_t)N_PTS * DIM * 2;
  float4* partials = (float4*)base;                                  // 16512*16 = 258 KiB
  unsigned char* lab8 = (unsigned char*)(base + (size_t)NBLK * 16);  // 8192 B

  normalize_kernel<<<N_PTS / 8, 256, 0, stream>>>(feat, labels, fb2, lab8);
  pair_kernel<<<NBLK / 4, 256, 0, stream>>>(fb2, lab8, partials);
  finalize_kernel<<<1, 1024, 0, stream>>>(partials, out);
}